// Round 14
// baseline (112.407 us; speedup 1.0000x reference)
//
#include <hip/hip_runtime.h>
#include <hip/hip_bf16.h>
#include <stdint.h>

// Problem constants
#define NROWS 8192
#define FDIM 256
#define MCOLS 20000
#define NT32 625           // 20000 / 32, exact -> no tail masking
#define MSPLIT 12          // grid 12 x 64 = 768 blocks = EXACTLY 3/CU (one generation)
#define NCLS 1000
#define LOG2E 1.44269504088896f
#define LN2   0.69314718055994f

// ws layout (bytes), total ~15.5 MB:
//   Mb2  bf16 memory, MFMA-fragment order : [0, 10240000)
//   Fb   bf16 box*5*log2e (row-major)     : [10240000, 14434304)
//   wsel weighted sel logits              : [14434304, 14467072)
//   pm   partial max [12][N]              : [14467072, 14991360)
//   ps   partial sum [12][N]              : [14991360, 15515648)
//   bpart block partials                  : [15515648, 15515776)

typedef short short8 __attribute__((ext_vector_type(8)));
typedef float f32x16 __attribute__((ext_vector_type(16)));

typedef __attribute__((address_space(3))) unsigned int lds_u32;
typedef const __attribute__((address_space(1))) unsigned int glb_u32;

__device__ __forceinline__ float ex2(float x) {   // raw v_exp_f32 (2^x), no ocml wrapper
    float r;
    asm("v_exp_f32 %0, %1" : "=v"(r) : "v"(x));
    return r;
}

__device__ __forceinline__ unsigned short f2bf(float x) {
    unsigned u = __float_as_uint(x);
    unsigned r = (u + 0x7FFFu + ((u >> 16) & 1u)) >> 16;   // RNE
    return (unsigned short)r;
}

// max of 16-vector via 3-ary nesting (clang can fuse to v_max3_f32)
__device__ __forceinline__ float vmax16(f32x16 v) {
    float x0 = fmaxf(fmaxf(v[0],  v[1]),  v[2]);
    float x1 = fmaxf(fmaxf(v[3],  v[4]),  v[5]);
    float x2 = fmaxf(fmaxf(v[6],  v[7]),  v[8]);
    float x3 = fmaxf(fmaxf(v[9],  v[10]), v[11]);
    float x4 = fmaxf(fmaxf(v[12], v[13]), v[14]);
    float x5 = fmaxf(fmaxf(x0, x1), x2);
    float x6 = fmaxf(fmaxf(x3, x4), v[15]);
    return fmaxf(x5, x6);
}

// Fb: row-major bf16, scaled by 5*log2(e).
__global__ void conv_kernel(const float* __restrict__ in, unsigned short* __restrict__ out,
                            int n4, float scale) {
    int idx = blockIdx.x * blockDim.x + threadIdx.x;
    if (idx >= n4) return;
    float4 v = ((const float4*)in)[idx];
    ushort4 o;
    o.x = f2bf(v.x * scale); o.y = f2bf(v.y * scale);
    o.z = f2bf(v.z * scale); o.w = f2bf(v.w * scale);
    ((ushort4*)out)[idx] = o;
}

// Mb2: memory in MFMA-fragment order. Granule g = (t*16 + kk)*64 + s (16 B each)
// holds Mem[t*32 + (s&31)][kk*16 + (s>>5)*8 .. +8] as bf16x8. A wave reading
// granules [kk*64 .. kk*64+64) of tile t gets exactly the 32x32x16 B-fragment
// in lane order (lane = s): contiguous, coalesced, swizzle-free.
__global__ void conv_mb2(const float* __restrict__ in, unsigned short* __restrict__ out) {
    int g = blockIdx.x * 256 + threadIdx.x;   // 640000 granules, grid 2500x256 exact
    int s = g & 63, kk = (g >> 6) & 15, t = g >> 10;
    const float* src = in + (size_t)(t * 32 + (s & 31)) * FDIM + kk * 16 + (s >> 5) * 8;
    float4 v0 = ((const float4*)src)[0];
    float4 v1 = ((const float4*)src)[1];
    short8 w;
    w[0] = (short)f2bf(v0.x); w[1] = (short)f2bf(v0.y);
    w[2] = (short)f2bf(v0.z); w[3] = (short)f2bf(v0.w);
    w[4] = (short)f2bf(v1.x); w[5] = (short)f2bf(v1.y);
    w[6] = (short)f2bf(v1.z); w[7] = (short)f2bf(v1.w);
    *(short8*)(out + (size_t)g * 8) = w;
}

// Selected logits: wsel[i] = 5 * sum_d d * dot(F[i], Mem[trace[label_i][d]]), fp32-exact,
// natural-log domain (independent of the exp2 trick in lse_gemm).
__global__ void sel_kernel(const int* __restrict__ gt, const float* __restrict__ F,
                           const float* __restrict__ Mem, const int* __restrict__ trace,
                           float* __restrict__ wsel) {
    int lane = threadIdx.x & 63, wid = threadIdx.x >> 6;
    int i = blockIdx.x * 4 + wid;
    int label = gt[i];
    float w = 0.0f;
    if (label >= 0 && label < NCLS) {
        float4 fv = ((const float4*)(F + (size_t)i * FDIM))[lane];
        #pragma unroll
        for (int d = 1; d <= 3; ++d) {
            int tr = trace[label * 4 + d];
            float4 mv = ((const float4*)(Mem + (size_t)tr * FDIM))[lane];
            float dot = fv.x*mv.x + fv.y*mv.y + fv.z*mv.z + fv.w*mv.w;
            #pragma unroll
            for (int off = 32; off >= 1; off >>= 1) dot += __shfl_xor(dot, off, 64);
            w += (float)d * dot;
        }
    }
    if (lane == 0) wsel[i] = w * 5.0f;   // 1/T
}

// Fused GEMM + online log2-sum-exp2 partials -- swapped-operand 32x32x16 on
// fragment-ordered Mb2, R13 body (2 independent accumulator chains, linear
// staging, 0 conflicts). GRID FIX: 768 blocks = exactly 3 resident/CU in ONE
// generation -- the former 1024-block grid ran a 256-block second generation
// at 1 wave/SIMD, dragging avg MfmaUtil from ~59% (gen-1) down to 43%.
__global__ __launch_bounds__(256, 2) void lse_gemm(
        const unsigned short* __restrict__ Fb, const unsigned short* __restrict__ Mb2,
        float* __restrict__ pm, float* __restrict__ ps) {
    __shared__ __align__(16) char smem[2 * 16384];  // 32 KiB, double-buffer

    const int split  = blockIdx.x;   // 0..11
    const int rowblk = blockIdx.y;   // 0..63
    const int tid  = threadIdx.x;
    const int lane = tid & 63, wid = tid >> 6;
    const int r0 = lane & 31;        // A-row within wave AND B-col
    const int hi = lane >> 5;        // k-slice half
    const int rowbase = rowblk * 128 + wid * 32;
    const int l16 = lane << 4;       // lane byte offset within a fragment

    // A fragments (Y-operand): lane holds row (rowbase + r0), k = kk*16 + hi*8 .. +8
    short8 a[16];
    #pragma unroll
    for (int kk = 0; kk < 16; ++kk)
        a[kk] = *(const short8*)(Fb + (size_t)(rowbase + r0) * FDIM + kk * 16 + hi * 8);

    float m = -3.0e38f, s = 0.0f;    // scalar online state: one row per lane

    const int t0 = (split * NT32) / MSPLIT;
    const int t1 = ((split + 1) * NT32) / MSPLIT;   // 52-53 tiles per split

    // Staging: verbatim linear copy of the 16KB fragment-ordered tile chunk.
#define STAGE(BUF, t)                                                              \
    do {                                                                           \
        const char* srcT = (const char*)Mb2 + (size_t)(t) * 16384 + l16;           \
        _Pragma("unroll")                                                          \
        for (int c = 0; c < 4; ++c) {                                              \
            __builtin_amdgcn_global_load_lds(                                      \
                (glb_u32*)(srcT + (wid * 4 + c) * 1024),                           \
                (lds_u32*)(smem + (BUF) * 16384 + (wid * 4 + c) * 1024),           \
                16, 0, 0);                                                         \
        }                                                                          \
    } while (0)

#define BODYC(BUF)                                                                 \
    do {                                                                           \
        const char* bp = smem + (BUF) * 16384 + l16;                               \
        f32x16 acc0 = {0,0,0,0,0,0,0,0,0,0,0,0,0,0,0,0};                           \
        f32x16 acc1 = {0,0,0,0,0,0,0,0,0,0,0,0,0,0,0,0};                           \
        __builtin_amdgcn_s_setprio(1);                                             \
        _Pragma("unroll")                                                          \
        for (int kk = 0; kk < 8; ++kk) {                                           \
            short8 b0 = *(const short8*)(bp + kk * 1024);                          \
            short8 b1 = *(const short8*)(bp + (kk + 8) * 1024);                    \
            acc0 = __builtin_amdgcn_mfma_f32_32x32x16_bf16(b0, a[kk],     acc0, 0, 0, 0); \
            acc1 = __builtin_amdgcn_mfma_f32_32x32x16_bf16(b1, a[kk + 8], acc1, 0, 0, 0); \
        }                                                                          \
        __builtin_amdgcn_s_setprio(0);                                             \
        f32x16 v = acc0 + acc1;                                                    \
        float nm = fmaxf(vmax16(v), m);                                            \
        float p0 = 0.f, p1 = 0.f, p2 = 0.f, p3 = 0.f;                              \
        _Pragma("unroll")                                                          \
        for (int i = 0; i < 16; i += 4) {                                          \
            p0 += ex2(v[i]     - nm); p1 += ex2(v[i + 1] - nm);                    \
            p2 += ex2(v[i + 2] - nm); p3 += ex2(v[i + 3] - nm);                    \
        }                                                                          \
        s = fmaf(s, ex2(m - nm), (p0 + p1) + (p2 + p3));                           \
        m = nm;                                                                    \
    } while (0)

    STAGE(0, t0);
    __syncthreads();

    int t = t0;
    while (t + 2 <= t1) {
        STAGE(1, t + 1);               // t+1 < t1 inside this loop
        BODYC(0);
        __syncthreads();
        if (t + 2 < t1) STAGE(0, t + 2);
        BODYC(1);
        __syncthreads();
        t += 2;
    }
    if (t < t1) BODYC(0);              // staged by the last iteration

#undef BODYC
#undef STAGE

    // Combine the two k-slice halves: lane l and l^32 hold the same row's two
    // 16-col subsets.
    {
        float om = __shfl_xor(m, 32, 64);
        float os = __shfl_xor(s, 32, 64);
        float nm = fmaxf(m, om);
        float sf = fmaf(s, ex2(m - nm), os * ex2(om - nm));
        if (lane < 32) {
            pm[split * NROWS + rowbase + lane] = nm;
            ps[split * NROWS + rowbase + lane] = sf;
        }
    }
}

__global__ void finalize_kernel(const int* __restrict__ gt, const float* __restrict__ wsel,
                                const float* __restrict__ pm, const float* __restrict__ ps,
                                float* __restrict__ bpart) {
    int tid = threadIdx.x;
    int i = blockIdx.x * 256 + tid;
    float mv[MSPLIT];
    float M = -3.0e38f;
    #pragma unroll
    for (int k = 0; k < MSPLIT; ++k) { mv[k] = pm[k * NROWS + i]; M = fmaxf(M, mv[k]); }
    float S = 0.0f;
    #pragma unroll
    for (int k = 0; k < MSPLIT; ++k) S += ps[k * NROWS + i] * ex2(mv[k] - M);
    float lse = (M + __log2f(S)) * LN2;   // back to natural-log domain
    int label = gt[i];
    float per = (label >= 0 && label < NCLS) ? (lse - wsel[i] * (1.0f / 6.0f)) : 0.0f;
    #pragma unroll
    for (int off = 32; off >= 1; off >>= 1) per += __shfl_xor(per, off, 64);
    __shared__ float red[4];
    int lane = tid & 63, wid = tid >> 6;
    if (lane == 0) red[wid] = per;
    __syncthreads();
    if (tid == 0) bpart[blockIdx.x] = red[0] + red[1] + red[2] + red[3];
}

__global__ void sum_kernel(const float* __restrict__ bpart, float* __restrict__ out) {
    int tid = threadIdx.x;
    float v = (tid < 32) ? bpart[tid] : 0.0f;
    #pragma unroll
    for (int off = 32; off >= 1; off >>= 1) v += __shfl_xor(v, off, 64);
    if (tid == 0) out[0] = 0.001f * v;
}

extern "C" void kernel_launch(void* const* d_in, const int* in_sizes, int n_in,
                              void* d_out, int out_size, void* d_ws, size_t ws_size,
                              hipStream_t stream) {
    const int*   gt    = (const int*)d_in[0];
    const float* F     = (const float*)d_in[1];
    const float* Mem   = (const float*)d_in[2];
    const int*   trace = (const int*)d_in[3];
    float* out = (float*)d_out;

    char* w = (char*)d_ws;
    unsigned short* Mb2 = (unsigned short*)w;
    unsigned short* Fb  = (unsigned short*)(w + 10240000);
    float* wsel  = (float*)(w + 14434304);
    float* pm    = (float*)(w + 14467072);
    float* ps    = (float*)(w + 14991360);
    float* bpart = (float*)(w + 15515648);

    conv_mb2<<<dim3(2500), dim3(256), 0, stream>>>(Mem, Mb2);
    conv_kernel<<<dim3((NROWS * FDIM / 4) / 256), dim3(256), 0, stream>>>(F, Fb, NROWS * FDIM / 4, 5.0f * LOG2E);
    sel_kernel<<<dim3(NROWS / 4), dim3(256), 0, stream>>>(gt, F, Mem, trace, wsel);
    lse_gemm<<<dim3(MSPLIT, NROWS / 128), dim3(256), 0, stream>>>(Fb, Mb2, pm, ps);
    finalize_kernel<<<dim3(NROWS / 256), dim3(256), 0, stream>>>(gt, wsel, pm, ps, bpart);
    sum_kernel<<<dim3(1), dim3(64), 0, stream>>>(bpart, out);
}

// Round 15
// 102.403 us; speedup vs baseline: 1.0977x; 1.0977x over previous
//
#include <hip/hip_runtime.h>
#include <hip/hip_bf16.h>
#include <stdint.h>

// Problem constants
#define NROWS 8192
#define FDIM 256
#define MCOLS 20000
#define NT32 625           // 20000 / 32, exact -> no tail masking
#define MSPLIT 16
#define NCLS 1000
#define LOG2E 1.44269504088896f
#define LN2   0.69314718055994f

// ws layout (bytes), total ~15.5 MB:
//   Mb2  bf16 memory, MFMA-fragment order : [0, 10240000)
//   Fb   bf16 box*5*log2e (row-major)     : [10240000, 14434304)
//   wsel weighted sel logits              : [14434304, 14467072)
//   pm   partial max [16][N]              : [14467072, 14991360)
//   ps   partial sum [16][N]              : [14991360, 15515648)
//   bpart block partials                  : [15515648, 15515776)

typedef short short8 __attribute__((ext_vector_type(8)));
typedef float f32x16 __attribute__((ext_vector_type(16)));

typedef __attribute__((address_space(3))) unsigned int lds_u32;
typedef const __attribute__((address_space(1))) unsigned int glb_u32;

__device__ __forceinline__ float ex2(float x) {   // raw v_exp_f32 (2^x), no ocml wrapper
    float r;
    asm("v_exp_f32 %0, %1" : "=v"(r) : "v"(x));
    return r;
}

__device__ __forceinline__ unsigned short f2bf(float x) {
    unsigned u = __float_as_uint(x);
    unsigned r = (u + 0x7FFFu + ((u >> 16) & 1u)) >> 16;   // RNE
    return (unsigned short)r;
}

// max of 16-vector via 3-ary nesting (clang can fuse to v_max3_f32)
__device__ __forceinline__ float vmax16(f32x16 v) {
    float x0 = fmaxf(fmaxf(v[0],  v[1]),  v[2]);
    float x1 = fmaxf(fmaxf(v[3],  v[4]),  v[5]);
    float x2 = fmaxf(fmaxf(v[6],  v[7]),  v[8]);
    float x3 = fmaxf(fmaxf(v[9],  v[10]), v[11]);
    float x4 = fmaxf(fmaxf(v[12], v[13]), v[14]);
    float x5 = fmaxf(fmaxf(x0, x1), x2);
    float x6 = fmaxf(fmaxf(x3, x4), v[15]);
    return fmaxf(x5, x6);
}

// Fb: row-major bf16, scaled by 5*log2(e).
__global__ void conv_kernel(const float* __restrict__ in, unsigned short* __restrict__ out,
                            int n4, float scale) {
    int idx = blockIdx.x * blockDim.x + threadIdx.x;
    if (idx >= n4) return;
    float4 v = ((const float4*)in)[idx];
    ushort4 o;
    o.x = f2bf(v.x * scale); o.y = f2bf(v.y * scale);
    o.z = f2bf(v.z * scale); o.w = f2bf(v.w * scale);
    ((ushort4*)out)[idx] = o;
}

// Mb2: memory in MFMA-fragment order. Granule g = (t*16 + kk)*64 + s (16 B each)
// holds Mem[t*32 + (s&31)][kk*16 + (s>>5)*8 .. +8] as bf16x8. A wave reading
// granules [kk*64 .. kk*64+64) of tile t gets exactly the 32x32x16 B-fragment
// in lane order (lane = s): contiguous, coalesced, swizzle-free.
__global__ void conv_mb2(const float* __restrict__ in, unsigned short* __restrict__ out) {
    int g = blockIdx.x * 256 + threadIdx.x;   // 640000 granules, grid 2500x256 exact
    int s = g & 63, kk = (g >> 6) & 15, t = g >> 10;
    const float* src = in + (size_t)(t * 32 + (s & 31)) * FDIM + kk * 16 + (s >> 5) * 8;
    float4 v0 = ((const float4*)src)[0];
    float4 v1 = ((const float4*)src)[1];
    short8 w;
    w[0] = (short)f2bf(v0.x); w[1] = (short)f2bf(v0.y);
    w[2] = (short)f2bf(v0.z); w[3] = (short)f2bf(v0.w);
    w[4] = (short)f2bf(v1.x); w[5] = (short)f2bf(v1.y);
    w[6] = (short)f2bf(v1.z); w[7] = (short)f2bf(v1.w);
    *(short8*)(out + (size_t)g * 8) = w;
}

// Selected logits: wsel[i] = 5 * sum_d d * dot(F[i], Mem[trace[label_i][d]]), fp32-exact,
// natural-log domain (independent of the exp2 trick in lse_gemm).
__global__ void sel_kernel(const int* __restrict__ gt, const float* __restrict__ F,
                           const float* __restrict__ Mem, const int* __restrict__ trace,
                           float* __restrict__ wsel) {
    int lane = threadIdx.x & 63, wid = threadIdx.x >> 6;
    int i = blockIdx.x * 4 + wid;
    int label = gt[i];
    float w = 0.0f;
    if (label >= 0 && label < NCLS) {
        float4 fv = ((const float4*)(F + (size_t)i * FDIM))[lane];
        #pragma unroll
        for (int d = 1; d <= 3; ++d) {
            int tr = trace[label * 4 + d];
            float4 mv = ((const float4*)(Mem + (size_t)tr * FDIM))[lane];
            float dot = fv.x*mv.x + fv.y*mv.y + fv.z*mv.z + fv.w*mv.w;
            #pragma unroll
            for (int off = 32; off >= 1; off >>= 1) dot += __shfl_xor(dot, off, 64);
            w += (float)d * dot;
        }
    }
    if (lane == 0) wsel[i] = w * 5.0f;   // 1/T
}

// Fused GEMM + online log2-sum-exp2 partials -- swapped-operand 32x32x16 on
// fragment-ordered Mb2, 64 ROWS PER WAVE: two A-sets (al/ah, 128 regs -- NOT
// pinned; low arch pressure lets the allocator AGPR-place them naturally as in
// R12/R13), each B-fragment read feeds TWO MFMAs -> 16 ds_read : 32 MFMA per
// wave-tile. LDS busy/CU halves to ~25us < the 33.6us MFMA floor -> matrix
// pipe binding. Block = 4 waves x 64 rows = 256 rows; grid 16x32 = 512 blocks
// = exactly 2/CU, one generation. Budget: ~160 AGPR + ~52 VGPR = 212 < 256.
__global__ __launch_bounds__(256, 2) void lse_gemm(
        const unsigned short* __restrict__ Fb, const unsigned short* __restrict__ Mb2,
        float* __restrict__ pm, float* __restrict__ ps) {
    __shared__ __align__(16) char smem[2 * 16384];  // 32 KiB, double-buffer

    const int split  = blockIdx.x;   // 0..15
    const int rowblk = blockIdx.y;   // 0..31
    const int tid  = threadIdx.x;
    const int lane = tid & 63, wid = tid >> 6;
    const int r0 = lane & 31;        // A-row within the 32-row half AND B-col
    const int hi = lane >> 5;        // k-slice half
    const int rowbase = rowblk * 256 + wid * 64;
    const int l16 = lane << 4;       // lane byte offset within a fragment

    // A fragments (Y-operand), two row-halves:
    //   al: row rowbase + r0, ah: row rowbase + 32 + r0; k = kk*16 + hi*8 .. +8
    short8 al[16], ah[16];
    #pragma unroll
    for (int kk = 0; kk < 16; ++kk) {
        al[kk] = *(const short8*)(Fb + (size_t)(rowbase + r0)      * FDIM + kk * 16 + hi * 8);
        ah[kk] = *(const short8*)(Fb + (size_t)(rowbase + 32 + r0) * FDIM + kk * 16 + hi * 8);
    }

    // scalar online state: one row per lane, per half
    float m0 = -3.0e38f, s0 = 0.0f, m1 = -3.0e38f, s1 = 0.0f;

    const int t0 = (split * NT32) / MSPLIT;
    const int t1 = ((split + 1) * NT32) / MSPLIT;   // 39-40 tiles per split

    // Staging: verbatim linear copy of the 16KB fragment-ordered tile chunk.
#define STAGE(BUF, t)                                                              \
    do {                                                                           \
        const char* srcT = (const char*)Mb2 + (size_t)(t) * 16384 + l16;           \
        _Pragma("unroll")                                                          \
        for (int c = 0; c < 4; ++c) {                                              \
            __builtin_amdgcn_global_load_lds(                                      \
                (glb_u32*)(srcT + (wid * 4 + c) * 1024),                           \
                (lds_u32*)(smem + (BUF) * 16384 + (wid * 4 + c) * 1024),           \
                16, 0, 0);                                                         \
        }                                                                          \
    } while (0)

#define BODYC(BUF)                                                                 \
    do {                                                                           \
        const char* bp = smem + (BUF) * 16384 + l16;                               \
        f32x16 accL = {0,0,0,0,0,0,0,0,0,0,0,0,0,0,0,0};                           \
        f32x16 accH = {0,0,0,0,0,0,0,0,0,0,0,0,0,0,0,0};                           \
        __builtin_amdgcn_s_setprio(1);                                             \
        _Pragma("unroll")                                                          \
        for (int kk = 0; kk < 16; ++kk) {                                          \
            short8 b = *(const short8*)(bp + kk * 1024);                           \
            accL = __builtin_amdgcn_mfma_f32_32x32x16_bf16(b, al[kk], accL, 0, 0, 0); \
            accH = __builtin_amdgcn_mfma_f32_32x32x16_bf16(b, ah[kk], accH, 0, 0, 0); \
        }                                                                          \
        __builtin_amdgcn_s_setprio(0);                                             \
        {                                                                          \
            float nm = fmaxf(vmax16(accL), m0);                                    \
            float p0 = 0.f, p1 = 0.f, p2 = 0.f, p3 = 0.f;                          \
            _Pragma("unroll")                                                      \
            for (int i = 0; i < 16; i += 4) {                                      \
                p0 += ex2(accL[i]     - nm); p1 += ex2(accL[i + 1] - nm);          \
                p2 += ex2(accL[i + 2] - nm); p3 += ex2(accL[i + 3] - nm);          \
            }                                                                      \
            s0 = fmaf(s0, ex2(m0 - nm), (p0 + p1) + (p2 + p3));                    \
            m0 = nm;                                                               \
        }                                                                          \
        {                                                                          \
            float nm = fmaxf(vmax16(accH), m1);                                    \
            float p0 = 0.f, p1 = 0.f, p2 = 0.f, p3 = 0.f;                          \
            _Pragma("unroll")                                                      \
            for (int i = 0; i < 16; i += 4) {                                      \
                p0 += ex2(accH[i]     - nm); p1 += ex2(accH[i + 1] - nm);          \
                p2 += ex2(accH[i + 2] - nm); p3 += ex2(accH[i + 3] - nm);          \
            }                                                                      \
            s1 = fmaf(s1, ex2(m1 - nm), (p0 + p1) + (p2 + p3));                    \
            m1 = nm;                                                               \
        }                                                                          \
    } while (0)

    STAGE(0, t0);
    __syncthreads();

    int t = t0;
    while (t + 2 <= t1) {
        STAGE(1, t + 1);               // t+1 < t1 inside this loop
        BODYC(0);
        __syncthreads();
        if (t + 2 < t1) STAGE(0, t + 2);
        BODYC(1);
        __syncthreads();
        t += 2;
    }
    if (t < t1) BODYC(0);              // staged by the last iteration

#undef BODYC
#undef STAGE

    // Combine the two k-slice halves: lane l and l^32 hold the same row's two
    // 16-col subsets (for both row-halves).
    {
        float om = __shfl_xor(m0, 32, 64);
        float os = __shfl_xor(s0, 32, 64);
        float nm = fmaxf(m0, om);
        float sf = fmaf(s0, ex2(m0 - nm), os * ex2(om - nm));
        if (lane < 32) {
            pm[split * NROWS + rowbase + lane] = nm;
            ps[split * NROWS + rowbase + lane] = sf;
        }
    }
    {
        float om = __shfl_xor(m1, 32, 64);
        float os = __shfl_xor(s1, 32, 64);
        float nm = fmaxf(m1, om);
        float sf = fmaf(s1, ex2(m1 - nm), os * ex2(om - nm));
        if (lane < 32) {
            pm[split * NROWS + rowbase + 32 + lane] = nm;
            ps[split * NROWS + rowbase + 32 + lane] = sf;
        }
    }
}

__global__ void finalize_kernel(const int* __restrict__ gt, const float* __restrict__ wsel,
                                const float* __restrict__ pm, const float* __restrict__ ps,
                                float* __restrict__ bpart) {
    int tid = threadIdx.x;
    int i = blockIdx.x * 256 + tid;
    float mv[MSPLIT];
    float M = -3.0e38f;
    #pragma unroll
    for (int k = 0; k < MSPLIT; ++k) { mv[k] = pm[k * NROWS + i]; M = fmaxf(M, mv[k]); }
    float S = 0.0f;
    #pragma unroll
    for (int k = 0; k < MSPLIT; ++k) S += ps[k * NROWS + i] * ex2(mv[k] - M);
    float lse = (M + __log2f(S)) * LN2;   // back to natural-log domain
    int label = gt[i];
    float per = (label >= 0 && label < NCLS) ? (lse - wsel[i] * (1.0f / 6.0f)) : 0.0f;
    #pragma unroll
    for (int off = 32; off >= 1; off >>= 1) per += __shfl_xor(per, off, 64);
    __shared__ float red[4];
    int lane = tid & 63, wid = tid >> 6;
    if (lane == 0) red[wid] = per;
    __syncthreads();
    if (tid == 0) bpart[blockIdx.x] = red[0] + red[1] + red[2] + red[3];
}

__global__ void sum_kernel(const float* __restrict__ bpart, float* __restrict__ out) {
    int tid = threadIdx.x;
    float v = (tid < 32) ? bpart[tid] : 0.0f;
    #pragma unroll
    for (int off = 32; off >= 1; off >>= 1) v += __shfl_xor(v, off, 64);
    if (tid == 0) out[0] = 0.001f * v;
}

extern "C" void kernel_launch(void* const* d_in, const int* in_sizes, int n_in,
                              void* d_out, int out_size, void* d_ws, size_t ws_size,
                              hipStream_t stream) {
    const int*   gt    = (const int*)d_in[0];
    const float* F     = (const float*)d_in[1];
    const float* Mem   = (const float*)d_in[2];
    const int*   trace = (const int*)d_in[3];
    float* out = (float*)d_out;

    char* w = (char*)d_ws;
    unsigned short* Mb2 = (unsigned short*)w;
    unsigned short* Fb  = (unsigned short*)(w + 10240000);
    float* wsel  = (float*)(w + 14434304);
    float* pm    = (float*)(w + 14467072);
    float* ps    = (float*)(w + 14991360);
    float* bpart = (float*)(w + 15515648);

    conv_mb2<<<dim3(2500), dim3(256), 0, stream>>>(Mem, Mb2);
    conv_kernel<<<dim3((NROWS * FDIM / 4) / 256), dim3(256), 0, stream>>>(F, Fb, NROWS * FDIM / 4, 5.0f * LOG2E);
    sel_kernel<<<dim3(NROWS / 4), dim3(256), 0, stream>>>(gt, F, Mem, trace, wsel);
    lse_gemm<<<dim3(MSPLIT, NROWS / 256), dim3(256), 0, stream>>>(Fb, Mb2, pm, ps);
    finalize_kernel<<<dim3(NROWS / 256), dim3(256), 0, stream>>>(gt, wsel, pm, ps, bpart);
    sum_kernel<<<dim3(1), dim3(64), 0, stream>>>(bpart, out);
}